// Round 1
// baseline (91.496 us; speedup 1.0000x reference)
//
#include <hip/hip_runtime.h>

// KFIoU loss: per-row 5-float (x,y,w,h,r) pred/target -> smooth-L1 xy loss +
// Kalman-filter IoU loss. Outputs: [loss.mean, xy_loss.mean, kf_loss.mean,
// KFIoU*3 (N elems)] concatenated flat, fp32.

__device__ __forceinline__ void cov_terms(float w, float h, float r,
                                          float& s11, float& s12, float& s22,
                                          float& V) {
    // clip like the reference
    w = fminf(fmaxf(w, 1e-7f), 1e7f);
    h = fminf(fmaxf(h, 1e-7f), 1e7f);
    float sn, cs;
    __sincosf(r, &sn, &cs);
    float sw = 0.25f * w * w;   // (0.5*w)^2
    float sh = 0.25f * h * h;
    s11 = cs * cs * sw + sn * sn * sh;
    s12 = cs * sn * (sw - sh);
    s22 = sn * sn * sw + cs * cs * sh;
    V = w * h;                  // uses clipped wh, as reference does
}

__device__ __forceinline__ float kf_elem(const float* P, const float* T,
                                         float& xyl, float& kfl) {
    // smooth-L1 on xy, beta = 1
    float dx = fabsf(P[0] - T[0]);
    float dy = fabsf(P[1] - T[1]);
    float lx = dx < 1.0f ? 0.5f * dx * dx : dx - 0.5f;
    float ly = dy < 1.0f ? 0.5f * dy * dy : dy - 0.5f;
    xyl = lx + ly;

    float ap, bp, dp, Vp, at, bt, dt, Vt;
    cov_terms(P[2], P[3], P[4], ap, bp, dp, Vp);
    cov_terms(T[2], T[3], T[4], at, bt, dt, Vt);

    // inv(Sp+St) = adj/det ; K = Sp*inv ; Sigma = Sp - K*Sp
    float A = ap + at, B = bp + bt, D = dp + dt;
    float invdet = 1.0f / (A * D - B * B);
    float K11 = (ap * D - bp * B) * invdet;
    float K12 = (bp * A - ap * B) * invdet;
    float K21 = (bp * D - dp * B) * invdet;
    float K22 = (dp * A - bp * B) * invdet;
    float S11 = ap - (K11 * ap + K12 * bp);
    float S12 = bp - (K11 * bp + K12 * dp);
    float S21 = bp - (K21 * ap + K22 * bp);
    float S22 = dp - (K21 * bp + K22 * dp);
    float detS = S11 * S22 - S12 * S21;
    float Vb = detS > 0.0f ? 4.0f * sqrtf(detS) : 0.0f;
    float kfiou = Vb / (Vp + Vt - Vb + 1e-6f);
    kfl = 1.0f - kfiou;
    return 3.0f * kfiou;
}

__global__ __launch_bounds__(256) void kf_main(
    const float* __restrict__ pred, const float* __restrict__ tgt,
    float* __restrict__ out, double* __restrict__ sums, int n4, int n)
{
    const int stride = gridDim.x * blockDim.x;
    double sl = 0.0, sx = 0.0, sk = 0.0;

    // main path: 4 rows (20 floats = 5 float4) per thread, fully coalesced
    for (int t = blockIdx.x * blockDim.x + threadIdx.x; t < n4; t += stride) {
        float P[20], T[20];
        const float4* p4 = reinterpret_cast<const float4*>(pred) + 5 * (size_t)t;
        const float4* t4 = reinterpret_cast<const float4*>(tgt) + 5 * (size_t)t;
#pragma unroll
        for (int j = 0; j < 5; ++j) {
            reinterpret_cast<float4*>(P)[j] = p4[j];
            reinterpret_cast<float4*>(T)[j] = t4[j];
        }
#pragma unroll
        for (int k = 0; k < 4; ++k) {
            float xyl, kfl;
            float k3 = kf_elem(P + 5 * k, T + 5 * k, xyl, kfl);
            out[3 + 4 * (size_t)t + k] = k3;
            sl += (double)fmaxf(xyl + kfl, 0.0f);
            sx += (double)xyl;
            sk += (double)kfl;
        }
    }

    // scalar tail (n % 4 rows) — dead for N=2M but keeps the kernel general
    for (int i = n4 * 4 + blockIdx.x * blockDim.x + threadIdx.x; i < n; i += stride) {
        float P[5], T[5];
#pragma unroll
        for (int j = 0; j < 5; ++j) {
            P[j] = pred[5 * (size_t)i + j];
            T[j] = tgt[5 * (size_t)i + j];
        }
        float xyl, kfl;
        float k3 = kf_elem(P, T, xyl, kfl);
        out[3 + (size_t)i] = k3;
        sl += (double)fmaxf(xyl + kfl, 0.0f);
        sx += (double)xyl;
        sk += (double)kfl;
    }

    // wave64 reduce (doubles)
#pragma unroll
    for (int off = 32; off > 0; off >>= 1) {
        sl += __shfl_down(sl, off);
        sx += __shfl_down(sx, off);
        sk += __shfl_down(sk, off);
    }
    __shared__ double smem[3][4];
    const int lane = threadIdx.x & 63;
    const int wave = threadIdx.x >> 6;
    if (lane == 0) {
        smem[0][wave] = sl; smem[1][wave] = sx; smem[2][wave] = sk;
    }
    __syncthreads();
    if (threadIdx.x == 0) {
        double a = 0, b = 0, c = 0;
#pragma unroll
        for (int w = 0; w < 4; ++w) { a += smem[0][w]; b += smem[1][w]; c += smem[2][w]; }
        atomicAdd(&sums[0], a);
        atomicAdd(&sums[1], b);
        atomicAdd(&sums[2], c);
    }
}

__global__ void kf_finalize(const double* __restrict__ sums,
                            float* __restrict__ out, double invn) {
    if (threadIdx.x == 0) {
        out[0] = (float)(sums[0] * invn);
        out[1] = (float)(sums[1] * invn);
        out[2] = (float)(sums[2] * invn);
    }
}

extern "C" void kernel_launch(void* const* d_in, const int* in_sizes, int n_in,
                              void* d_out, int out_size, void* d_ws, size_t ws_size,
                              hipStream_t stream) {
    const float* pred = (const float*)d_in[0];
    const float* tgt  = (const float*)d_in[1];
    float* out = (float*)d_out;
    double* sums = (double*)d_ws;

    const int n  = in_sizes[0] / 5;   // 2,000,000
    const int n4 = n / 4;             // 500,000 row-quads

    hipMemsetAsync(d_ws, 0, 3 * sizeof(double), stream);

    int blocks = (n4 + 255) / 256;
    if (blocks > 2048) blocks = 2048;
    kf_main<<<blocks, 256, 0, stream>>>(pred, tgt, out, sums, n4, n);
    kf_finalize<<<1, 64, 0, stream>>>(sums, out, 1.0 / (double)n);
}

// Round 2
// 24.363 us; speedup vs baseline: 3.7556x; 3.7556x over previous
//
#include <hip/hip_runtime.h>

// KFIoU loss: per-row 5-float (x,y,w,h,r) pred/target -> smooth-L1 xy loss +
// Kalman-filter IoU loss. Outputs: [loss.mean, xy_loss.mean, kf_loss.mean,
// KFIoU*3 (N elems)] concatenated flat, fp32.
//
// R1 lesson: 2048 same-address atomicAdd(double) serialized ~60us tail.
// Now: block partials to distinct d_ws slots + separate reduce kernel.

#define NBLK 2048

__device__ __forceinline__ void cov_terms(float w, float h, float r,
                                          float& s11, float& s12, float& s22,
                                          float& V) {
    w = fminf(fmaxf(w, 1e-7f), 1e7f);
    h = fminf(fmaxf(h, 1e-7f), 1e7f);
    float sn, cs;
    __sincosf(r, &sn, &cs);
    float sw = 0.25f * w * w;   // (0.5*w)^2
    float sh = 0.25f * h * h;
    s11 = cs * cs * sw + sn * sn * sh;
    s12 = cs * sn * (sw - sh);
    s22 = sn * sn * sw + cs * cs * sh;
    V = w * h;
}

__device__ __forceinline__ float kf_elem(const float* P, const float* T,
                                         float& xyl, float& kfl) {
    float dx = fabsf(P[0] - T[0]);
    float dy = fabsf(P[1] - T[1]);
    float lx = dx < 1.0f ? 0.5f * dx * dx : dx - 0.5f;
    float ly = dy < 1.0f ? 0.5f * dy * dy : dy - 0.5f;
    xyl = lx + ly;

    float ap, bp, dp, Vp, at, bt, dt, Vt;
    cov_terms(P[2], P[3], P[4], ap, bp, dp, Vp);
    cov_terms(T[2], T[3], T[4], at, bt, dt, Vt);

    // inv(Sp+St) = adj/det ; K = Sp*inv ; Sigma = Sp - K*Sp
    float A = ap + at, B = bp + bt, D = dp + dt;
    float invdet = 1.0f / (A * D - B * B);
    float K11 = (ap * D - bp * B) * invdet;
    float K12 = (bp * A - ap * B) * invdet;
    float K21 = (bp * D - dp * B) * invdet;
    float K22 = (dp * A - bp * B) * invdet;
    float S11 = ap - (K11 * ap + K12 * bp);
    float S12 = bp - (K11 * bp + K12 * dp);
    float S21 = bp - (K21 * ap + K22 * bp);
    float S22 = dp - (K21 * bp + K22 * dp);
    float detS = S11 * S22 - S12 * S21;
    float Vb = detS > 0.0f ? 4.0f * sqrtf(detS) : 0.0f;
    float kfiou = Vb / (Vp + Vt - Vb + 1e-6f);
    kfl = 1.0f - kfiou;
    return 3.0f * kfiou;
}

__global__ __launch_bounds__(256) void kf_main(
    const float* __restrict__ pred, const float* __restrict__ tgt,
    float* __restrict__ out, float* __restrict__ partials, int n4, int n)
{
    const int stride = gridDim.x * blockDim.x;
    float sl = 0.0f, sx = 0.0f, sk = 0.0f;

    // 4 rows (20 floats = 5 float4) per thread, fully coalesced
    for (int t = blockIdx.x * blockDim.x + threadIdx.x; t < n4; t += stride) {
        float P[20], T[20];
        const float4* p4 = reinterpret_cast<const float4*>(pred) + 5 * (size_t)t;
        const float4* t4 = reinterpret_cast<const float4*>(tgt) + 5 * (size_t)t;
#pragma unroll
        for (int j = 0; j < 5; ++j) {
            reinterpret_cast<float4*>(P)[j] = p4[j];
            reinterpret_cast<float4*>(T)[j] = t4[j];
        }
#pragma unroll
        for (int k = 0; k < 4; ++k) {
            float xyl, kfl;
            float k3 = kf_elem(P + 5 * k, T + 5 * k, xyl, kfl);
            out[3 + 4 * (size_t)t + k] = k3;
            sl += fmaxf(xyl + kfl, 0.0f);
            sx += xyl;
            sk += kfl;
        }
    }

    // scalar tail (dead for N=2M, kept for generality)
    for (int i = n4 * 4 + blockIdx.x * blockDim.x + threadIdx.x; i < n; i += stride) {
        float P[5], T[5];
#pragma unroll
        for (int j = 0; j < 5; ++j) {
            P[j] = pred[5 * (size_t)i + j];
            T[j] = tgt[5 * (size_t)i + j];
        }
        float xyl, kfl;
        float k3 = kf_elem(P, T, xyl, kfl);
        out[3 + (size_t)i] = k3;
        sl += fmaxf(xyl + kfl, 0.0f);
        sx += xyl;
        sk += kfl;
    }

    // wave64 tree reduce (fp32)
#pragma unroll
    for (int off = 32; off > 0; off >>= 1) {
        sl += __shfl_down(sl, off);
        sx += __shfl_down(sx, off);
        sk += __shfl_down(sk, off);
    }
    __shared__ float smem[3][4];
    const int lane = threadIdx.x & 63;
    const int wave = threadIdx.x >> 6;
    if (lane == 0) {
        smem[0][wave] = sl; smem[1][wave] = sx; smem[2][wave] = sk;
    }
    __syncthreads();
    if (threadIdx.x == 0) {
        float a = 0, b = 0, c = 0;
#pragma unroll
        for (int w = 0; w < 4; ++w) { a += smem[0][w]; b += smem[1][w]; c += smem[2][w]; }
        // SoA: distinct addresses, no atomics
        partials[blockIdx.x]            = a;
        partials[NBLK + blockIdx.x]     = b;
        partials[2 * NBLK + blockIdx.x] = c;
    }
}

__global__ __launch_bounds__(256) void kf_reduce(
    const float* __restrict__ partials, float* __restrict__ out, double invn)
{
    double a = 0, b = 0, c = 0;
    for (int i = threadIdx.x; i < NBLK; i += 256) {
        a += (double)partials[i];
        b += (double)partials[NBLK + i];
        c += (double)partials[2 * NBLK + i];
    }
#pragma unroll
    for (int off = 32; off > 0; off >>= 1) {
        a += __shfl_down(a, off);
        b += __shfl_down(b, off);
        c += __shfl_down(c, off);
    }
    __shared__ double smem[3][4];
    const int lane = threadIdx.x & 63;
    const int wave = threadIdx.x >> 6;
    if (lane == 0) {
        smem[0][wave] = a; smem[1][wave] = b; smem[2][wave] = c;
    }
    __syncthreads();
    if (threadIdx.x == 0) {
        double ra = 0, rb = 0, rc = 0;
#pragma unroll
        for (int w = 0; w < 4; ++w) { ra += smem[0][w]; rb += smem[1][w]; rc += smem[2][w]; }
        out[0] = (float)(ra * invn);
        out[1] = (float)(rb * invn);
        out[2] = (float)(rc * invn);
    }
}

extern "C" void kernel_launch(void* const* d_in, const int* in_sizes, int n_in,
                              void* d_out, int out_size, void* d_ws, size_t ws_size,
                              hipStream_t stream) {
    const float* pred = (const float*)d_in[0];
    const float* tgt  = (const float*)d_in[1];
    float* out = (float*)d_out;
    float* partials = (float*)d_ws;   // 3 * NBLK floats

    const int n  = in_sizes[0] / 5;   // 2,000,000
    const int n4 = n / 4;             // 500,000 row-quads

    kf_main<<<NBLK, 256, 0, stream>>>(pred, tgt, out, partials, n4, n);
    kf_reduce<<<1, 256, 0, stream>>>(partials, out, 1.0 / (double)n);
}